// Round 1
// baseline (75.552 us; speedup 1.0000x reference)
//
#include <hip/hip_runtime.h>

// Fused: y = upsample_nearest2x(conv1x1(x, W, b))  ==  conv on small grid, replicate 8x.
// x: [2][320][16][32][32] f32, W: [160][320] f32, b: [160] f32
// out: [2][160][32][64][64] f32

#define B_    2
#define CI    320
#define CO    160
#define DD    16
#define HH    32
#define WW    32
#define S_IN  (DD * HH * WW)   // 16384
#define KC    32               // K chunk
#define NT    64               // spatial tile per block (2 full w-rows)

__global__ __launch_bounds__(256) void fused_upconv_kernel(
    const float* __restrict__ x,
    const float* __restrict__ Wm,
    const float* __restrict__ bias,
    float* __restrict__ out)
{
    __shared__ float Xs[KC][NT];        // 8 KB
    __shared__ float Ws[CO][KC + 4];    // pad 32->36 words: rows 144B (16B aligned), banks spread

    const int t    = threadIdx.x;
    const int tile = blockIdx.x;        // 0..255  (16384/64)
    const int b    = blockIdx.y;        // 0..1
    const int s_base = tile * NT;

    const int sg = t & 15;              // s-group: 16 groups of 4 consecutive s
    const int og = t >> 4;              // o-group: 16 groups of 10 o
    const int s0 = s_base + sg * 4;     // this thread's first (global) small-spatial idx
    const int o0 = og * 10;

    float acc[10][4];
    #pragma unroll
    for (int i = 0; i < 10; ++i)
        #pragma unroll
        for (int j = 0; j < 4; ++j) acc[i][j] = 0.f;

    const float* xb = x + (size_t)b * CI * S_IN;

    for (int kc = 0; kc < CI; kc += KC) {
        __syncthreads();
        // stage Xs[kk][j] = x[b][kc+kk][s_base+j]  (2048 elems, coalesced 256B rows)
        #pragma unroll
        for (int it = 0; it < (KC * NT) / 256; ++it) {
            int idx = t + it * 256;
            int kk = idx >> 6, j = idx & 63;
            Xs[kk][j] = xb[(size_t)(kc + kk) * S_IN + s_base + j];
        }
        // stage Ws[o][cc] = W[o][kc+cc]  (5120 elems, coalesced 128B rows)
        #pragma unroll
        for (int it = 0; it < (CO * KC) / 256; ++it) {
            int idx = t + it * 256;
            int o = idx >> 5, cc = idx & 31;
            Ws[o][cc] = Wm[o * CI + kc + cc];
        }
        __syncthreads();

        #pragma unroll
        for (int kk = 0; kk < KC; kk += 4) {
            // 4 k-slices of x for my 4 s (ds_read_b128 each)
            float4 xv[4];
            #pragma unroll
            for (int u = 0; u < 4; ++u)
                xv[u] = *reinterpret_cast<const float4*>(&Xs[kk + u][sg * 4]);
            const float xf[4][4] = {
                {xv[0].x, xv[0].y, xv[0].z, xv[0].w},
                {xv[1].x, xv[1].y, xv[1].z, xv[1].w},
                {xv[2].x, xv[2].y, xv[2].z, xv[2].w},
                {xv[3].x, xv[3].y, xv[3].z, xv[3].w}};
            #pragma unroll
            for (int i = 0; i < 10; ++i) {
                float4 wv = *reinterpret_cast<const float4*>(&Ws[o0 + i][kk]);
                #pragma unroll
                for (int j = 0; j < 4; ++j) {
                    acc[i][j] += wv.x * xf[0][j];
                    acc[i][j] += wv.y * xf[1][j];
                    acc[i][j] += wv.z * xf[2][j];
                    acc[i][j] += wv.w * xf[3][j];
                }
            }
        }
    }

    // epilogue: add bias, replicate each small result to 8 output positions.
    // s0..s0+3 lie in one w-row: d = s0>>10, h = (s0>>5)&31, w = s0&31 (w%4==0).
    const int d = s0 >> 10;
    const int h = (s0 >> 5) & 31;
    const int w = s0 & 31;

    #pragma unroll
    for (int i = 0; i < 10; ++i) {
        const int o = o0 + i;
        const float bo = bias[o];
        const float v0 = acc[i][0] + bo, v1 = acc[i][1] + bo;
        const float v2 = acc[i][2] + bo, v3 = acc[i][3] + bo;
        const float4 p01 = make_float4(v0, v0, v1, v1);
        const float4 p23 = make_float4(v2, v2, v3, v3);
        const size_t chan_base = ((size_t)(b * CO + o)) * (32 * 64 * 64);
        #pragma unroll
        for (int r0 = 0; r0 < 2; ++r0) {
            #pragma unroll
            for (int r1 = 0; r1 < 2; ++r1) {
                size_t off = chan_base
                           + (size_t)(2 * d + r0) * (64 * 64)
                           + (size_t)(2 * h + r1) * 64
                           + (size_t)(2 * w);
                *reinterpret_cast<float4*>(&out[off])     = p01;
                *reinterpret_cast<float4*>(&out[off + 4]) = p23;
            }
        }
    }
}

extern "C" void kernel_launch(void* const* d_in, const int* in_sizes, int n_in,
                              void* d_out, int out_size, void* d_ws, size_t ws_size,
                              hipStream_t stream) {
    const float* x    = (const float*)d_in[0];
    const float* Wm   = (const float*)d_in[1];
    const float* bias = (const float*)d_in[2];
    float* out        = (float*)d_out;

    dim3 grid(S_IN / NT, B_);   // (256, 2)
    dim3 block(256);
    fused_upconv_kernel<<<grid, block, 0, stream>>>(x, Wm, bias, out);
}

// Round 2
// 40.259 us; speedup vs baseline: 1.8766x; 1.8766x over previous
//
#include <hip/hip_runtime.h>
#include <hip/hip_bf16.h>

// y = upsample_nearest_2x2x2(conv1x1(x,W,b)); conv on small grid via bf16 MFMA, replicate 8x.
// x: [2][320][16][32][32] f32, W: [160][320] f32, b: [160] f32 -> out: [2][160][32][64][64] f32

#define CI     320
#define CO     160
#define S_IN   16384      // 16*32*32
#define KC     32         // K chunk = one MFMA K-step
#define NT     64         // spatial tile per block
#define NCHUNK (CI / KC)  // 10
#define MT     (CO / 16)  // 10 M-tiles

typedef __attribute__((ext_vector_type(8))) short short8;
typedef __attribute__((ext_vector_type(4))) float f32x4;

static __device__ __forceinline__ unsigned short f2bf(float f) {
    __hip_bfloat16 h = __float2bfloat16(f);   // RNE
    unsigned short u;
    __builtin_memcpy(&u, &h, 2);
    return u;
}
static __device__ __forceinline__ unsigned int pack2(float lo, float hi) {
    return (unsigned int)f2bf(lo) | ((unsigned int)f2bf(hi) << 16);
}

__global__ __launch_bounds__(256) void fused_upconv_mfma(
    const float* __restrict__ x,
    const float* __restrict__ Wm,
    const float* __restrict__ bias,
    float* __restrict__ out)
{
    // bf16 tiles, rows padded to 80 B (20 u32): 16B-aligned rows, ~2-way banks only
    __shared__ unsigned int XsU[NT][20];   // [s][k/2]  (k fastest, bf16 pairs)  5.0 KB
    __shared__ unsigned int WsU[CO][20];   // [o][k/2]                          12.5 KB

    const int t      = threadIdx.x;
    const int tile   = blockIdx.x;          // 0..255
    const int b      = blockIdx.y;          // 0..1
    const int s_base = tile * NT;
    const float* xb  = x + (size_t)b * CI * S_IN;

    // ---- staging maps (disjoint coverage by 256 threads) ----
    // X: thread -> (k-pair kp = t>>4 in 0..15, s4 = (t&15)*4): 2 float4 loads, 4 u32 LDS writes
    const int kp = t >> 4;
    const int s4 = (t & 15) * 4;
    // W: 5 iters: o = (t>>3) + it*32, kq = t&7: 1 float4 load + 1 uint2 LDS write each
    const int ow = t >> 3;
    const int kq = t & 7;

    float4 xr0, xr1;
    float4 wr[5];

    // prefetch chunk 0
    {
        const int kc = 0;
        xr0 = *(const float4*)&xb[(size_t)(kc + 2 * kp)     * S_IN + s_base + s4];
        xr1 = *(const float4*)&xb[(size_t)(kc + 2 * kp + 1) * S_IN + s_base + s4];
        #pragma unroll
        for (int it = 0; it < 5; ++it)
            wr[it] = *(const float4*)&Wm[(size_t)(ow + it * 32) * CI + kc + kq * 4];
    }

    // ---- fragment indices ----
    const int lane = t & 63;
    const int wid  = t >> 6;        // wave id 0..3 -> N-subtile of 16 s
    const int frow = lane & 15;     // A: o row / B: s col / D: s col
    const int fk   = lane >> 4;     // k-slot (8 bf16) / D: o row group

    f32x4 acc[MT];
    #pragma unroll
    for (int mt = 0; mt < MT; ++mt) acc[mt] = (f32x4){0.f, 0.f, 0.f, 0.f};

    const char* xrow = (const char*)(&XsU[wid * 16 + frow][0]) + fk * 16;

    for (int c = 0; c < NCHUNK; ++c) {
        __syncthreads();   // previous chunk's fragment reads complete

        // stage regs -> LDS (cvt f32->bf16 here; compiler waits vmcnt as needed)
        {
            float xa[4] = {xr0.x, xr0.y, xr0.z, xr0.w};
            float xc[4] = {xr1.x, xr1.y, xr1.z, xr1.w};
            #pragma unroll
            for (int j = 0; j < 4; ++j)
                XsU[s4 + j][kp] = pack2(xa[j], xc[j]);   // k=2kp low, 2kp+1 high
            #pragma unroll
            for (int it = 0; it < 5; ++it) {
                uint2 p = make_uint2(pack2(wr[it].x, wr[it].y), pack2(wr[it].z, wr[it].w));
                *(uint2*)&WsU[ow + it * 32][kq * 2] = p;
            }
        }
        __syncthreads();

        // prefetch next chunk (overlaps MFMA below)
        if (c < NCHUNK - 1) {
            const int kc = (c + 1) * KC;
            xr0 = *(const float4*)&xb[(size_t)(kc + 2 * kp)     * S_IN + s_base + s4];
            xr1 = *(const float4*)&xb[(size_t)(kc + 2 * kp + 1) * S_IN + s_base + s4];
            #pragma unroll
            for (int it = 0; it < 5; ++it)
                wr[it] = *(const float4*)&Wm[(size_t)(ow + it * 32) * CI + kc + kq * 4];
        }

        // compute: B fragment (this wave's 16 s), then 10 M-tiles
        const short8 bfrag = *(const short8*)xrow;
        #pragma unroll
        for (int mt = 0; mt < MT; ++mt) {
            const short8 afrag =
                *(const short8*)((const char*)(&WsU[mt * 16 + frow][0]) + fk * 16);
            acc[mt] = __builtin_amdgcn_mfma_f32_16x16x32_bf16(afrag, bfrag, acc[mt], 0, 0, 0);
        }
    }

    // ---- epilogue: bias + replicate 8x; shfl-pair -> full float4 (128B-line) stores ----
    const int s   = s_base + wid * 16 + frow;   // D col = s  (m89-verified layout)
    const int dd  = s >> 10;
    const int hh  = (s >> 5) & 31;
    const int wc  = s & 31;
    const int odd = lane & 1;
    const int wc0 = wc & ~1;                    // even partner's w-col

    #pragma unroll
    for (int mt = 0; mt < MT; ++mt) {
        #pragma unroll
        for (int j = 0; j < 4; ++j) {
            const int o = mt * 16 + fk * 4 + j; // D row = o
            float v  = acc[mt][j] + bias[o];
            float vp = __shfl_xor(v, 1);
            float lo = odd ? vp : v;
            float hi = odd ? v : vp;
            float4 q = make_float4(lo, lo, hi, hi);
            // even lane writes d-row 2d, odd lane 2d+1; each writes h-rows 2h and 2h+1
            const size_t base = (((size_t)(b * CO + o) * 32) + (size_t)(2 * dd + odd)) * 4096
                              + (size_t)(2 * hh) * 64 + (size_t)(2 * wc0);
            *(float4*)&out[base]      = q;
            *(float4*)&out[base + 64] = q;
        }
    }
}

extern "C" void kernel_launch(void* const* d_in, const int* in_sizes, int n_in,
                              void* d_out, int out_size, void* d_ws, size_t ws_size,
                              hipStream_t stream) {
    const float* x    = (const float*)d_in[0];
    const float* Wm   = (const float*)d_in[1];
    const float* bias = (const float*)d_in[2];
    float* out        = (float*)d_out;

    dim3 grid(S_IN / NT, 2);   // (256, 2) = 512 blocks
    dim3 block(256);
    fused_upconv_mfma<<<grid, block, 0, stream>>>(x, Wm, bias, out);
}